// Round 19
// baseline (105.163 us; speedup 1.0000x reference)
//
#include <hip/hip_runtime.h>
#include <math.h>

typedef unsigned short u16;
typedef unsigned int u32;
typedef __bf16 bf16x8 __attribute__((ext_vector_type(8)));
typedef float f32x4 __attribute__((ext_vector_type(4)));
typedef unsigned short ushort4v __attribute__((ext_vector_type(4)));

#define T_SEQ 2048
#define WIN_M1 523                 // WINDOW-1
#define QSCALE 0.180336879f        // 0.125 * log2(e): scores in log2 domain
#define MASKV -1e30f

__device__ __forceinline__ u16 f2b(float f) {
  union { float f; unsigned int u; } v; v.f = f;
  unsigned int u = v.u;
  u += 0x7FFFu + ((u >> 16) & 1u);
  return (u16)(u >> 16);
}

__device__ __forceinline__ u32 cvtpk(float lo, float hi) {
  union { __bf16 h[2]; u32 d; } cv;
  cv.h[0] = (__bf16)lo;
  cv.h[1] = (__bf16)hi;
  return cv.d;
}

__device__ __forceinline__ float fexp2(float x) {
  return __builtin_amdgcn_exp2f(x);
}

// ================= FRAGMENT-ORDERED LAYOUTS (R16 win, now for EVERYTHING) ==
// 16-row x 32-k block of 512 elems (1KB): element (row, k) lives at
//   blk = (row/16)*(K/32) + k/32,  off = ((k>>3)&3)*128 + (row&15)*8 + (k&7)
// Reader lane L (= q4*16+l15) reads blk<<9 + L*8 -> one contiguous 1KB/instr.
//   xf/Yf: rows = M (4096), K = 1024.   Wf (cat, per-z region) / WoTf: n rows.
//   Qf/Kf: [bh][t16][kb][lane][8]; Vf: [bh][kv32][jo][lane][8] (R16).
// ===========================================================================

// ---- fused prep: convert x -> xf (frag) + transpose 4 weights -> Wf (frag) ----
__global__ void prep_k(const float* __restrict__ x, u16* __restrict__ xf,
                       const float* __restrict__ W0, const float* __restrict__ W1,
                       const float* __restrict__ W2, const float* __restrict__ W3,
                       u16* __restrict__ WcatF, u16* __restrict__ WoF) {
  const int bid = blockIdx.x;
  if (bid < 4096) {
    int i = bid * 256 + threadIdx.x;   // float4 index; row = i>>8, k = (i&255)*4
    const int row = i >> 8, k = (i & 255) * 4;
    float4 v = ((const float4*)x)[i];
    ushort4v p = {f2b(v.x), f2b(v.y), f2b(v.z), f2b(v.w)};
    const size_t blk = ((size_t)(row >> 4) * 32 + (k >> 5)) << 9;
    const size_t off = (size_t)((k >> 3) & 3) * 128 + (size_t)(row & 15) * 8 + (k & 7);
    *(ushort4v*)(xf + blk + off) = p;
    return;
  }
  __shared__ float tile[32][33];
  const int t = bid - 4096;
  const int z = t >> 10, i = t & 1023;
  const float* W = (z == 0) ? W0 : (z == 1) ? W1 : (z == 2) ? W2 : W3;
  u16* Wt = (z < 3) ? (WcatF + (size_t)z * 1024 * 1024) : WoF;
  int tx = threadIdx.x & 31, ty = threadIdx.x >> 5;  // 32 x 8
  int n0 = (i & 31) * 32, k0 = (i >> 5) * 32;
#pragma unroll
  for (int j = 0; j < 4; ++j)
    tile[ty + j * 8][tx] = W[(size_t)(k0 + ty + j * 8) * 1024 + n0 + tx];
  __syncthreads();
#pragma unroll
  for (int j = 0; j < 4; ++j) {
    const int n = n0 + ty + j * 8, k = k0 + tx;
    const size_t blk = ((size_t)(n >> 4) * 32 + (k >> 5)) << 9;
    const size_t off = (size_t)((k >> 3) & 3) * 128 + (size_t)(n & 15) * 8 + (k & 7);
    Wt[blk + off] = f2b(tile[tx][ty + j * 8]);
  }
}

// ---- QKV GEMM: NO LDS, NO BARRIERS. 128x128 tile, 4 waves, reg dbuf. ----
// R19: staged-LDS lockstep was the wall (R16-R18: ~1000cyc/block-step at any
// tile size). All operands fragment-ordered -> every A/B fragment load is
// one contiguous 1KB instr from global (attn's proven streaming pattern).
// Blocks fully independent: 768 blocks = 3/CU = 3 indep waves/SIMD.
__global__ __launch_bounds__(256) void gemm_qkv(
    const u16* __restrict__ A, const u16* __restrict__ Bt,
    u16* __restrict__ Qo, u16* __restrict__ Ko, u16* __restrict__ Vto,
    const float* __restrict__ rc, const float* __restrict__ rs) {
  const int lane = threadIdx.x & 63, w = threadIdx.x >> 6;
  const int l15 = lane & 15, q4 = lane >> 4;
  // XCD-chunked: XCD owns 3 col-panels x 32 row-blocks (B 768KB -> its L2)
  const int g = blockIdx.x, xcd = g & 7, idx = g >> 3;  // idx 0..95
  const int bx = xcd * 3 + idx % 3, by = idx / 3;
  const int row0 = by * 128, col0 = bx * 128;
  const int wm = w >> 1, wn = w & 1;
  const u16* Ab = A + (((size_t)((row0 >> 4) + wm * 4) * 32) << 9) + lane * 8;
  const u16* Bb = Bt + (((size_t)((col0 >> 4) + wn * 4) * 32) << 9) + lane * 8;

  f32x4 acc[4][4];
#pragma unroll
  for (int i = 0; i < 4; ++i)
#pragma unroll
    for (int j = 0; j < 4; ++j) acc[i][j] = (f32x4){0.f, 0.f, 0.f, 0.f};

  bf16x8 ac[4], an[4], bc[4], bn[4];
#pragma unroll
  for (int im = 0; im < 4; ++im) ac[im] = *(const bf16x8*)(Ab + ((size_t)(im * 32) << 9));
#pragma unroll
  for (int jn = 0; jn < 4; ++jn) bc[jn] = *(const bf16x8*)(Bb + ((size_t)(jn * 32) << 9));

  for (int t = 0; t < 32; t += 2) {
#pragma unroll
    for (int im = 0; im < 4; ++im) an[im] = *(const bf16x8*)(Ab + ((size_t)(im * 32 + t + 1) << 9));
#pragma unroll
    for (int jn = 0; jn < 4; ++jn) bn[jn] = *(const bf16x8*)(Bb + ((size_t)(jn * 32 + t + 1) << 9));
#pragma unroll
    for (int im = 0; im < 4; ++im)
#pragma unroll
      for (int jn = 0; jn < 4; ++jn)
        acc[im][jn] = __builtin_amdgcn_mfma_f32_16x16x32_bf16(ac[im], bc[jn], acc[im][jn], 0, 0, 0);
    if (t + 2 < 32) {
#pragma unroll
      for (int im = 0; im < 4; ++im) ac[im] = *(const bf16x8*)(Ab + ((size_t)(im * 32 + t + 2) << 9));
#pragma unroll
      for (int jn = 0; jn < 4; ++jn) bc[jn] = *(const bf16x8*)(Bb + ((size_t)(jn * 32 + t + 2) << 9));
    }
#pragma unroll
    for (int im = 0; im < 4; ++im)
#pragma unroll
      for (int jn = 0; jn < 4; ++jn)
        acc[im][jn] = __builtin_amdgcn_mfma_f32_16x16x32_bf16(an[im], bn[jn], acc[im][jn], 0, 0, 0);
  }

  // Epilogue: RoPE Q/K + fragment-ordered scatter (R16-verified).
#pragma unroll
  for (int im = 0; im < 4; ++im) {
    const int rowb = row0 + wm * 64 + im * 16 + q4 * 4;
    const int b = rowb >> 11, t0 = rowb & 2047;
#pragma unroll
    for (int jn = 0; jn < 2; ++jn) {
      const int n = col0 + wn * 64 + jn * 16 + l15;
      const int sel = n >> 10, nn = n & 1023;
      const int h = nn >> 6, hd = nn & 63;  // in [0,32)
      const int bhi = b * 16 + h;
      if (sel < 2) {
        const float qs = (sel == 0) ? QSCALE : 1.0f;
        u16* base = (sel == 0 ? Qo : Ko);
        const int q4c = (hd >> 3) & 3, e = hd & 7;
#pragma unroll
        for (int r = 0; r < 4; ++r) {
          const int tt = t0 + r;
          const float c = rc[tt * 32 + hd], s = rs[tt * 32 + hd];
          const float x1 = acc[im][jn][r], x2 = acc[im][jn + 2][r];
          const size_t blk = ((size_t)bhi * 128 + (tt >> 4)) * 2;
          const size_t off = (size_t)q4c * 128 + (size_t)(tt & 15) * 8 + e;
          base[(blk << 9) + off] = f2b((x1 * c + x2 * s) * qs);
          base[((blk + 1) << 9) + off] = f2b((x1 * c - x2 * s) * qs);
        }
      } else {
        const int kv32 = t0 >> 5;
        const int q4w = (t0 >> 3) & 3;
        const int e0 = t0 & 7;           // in {0,4}
        const int jo1 = hd >> 4;
        const int l15r = hd & 15;
        ushort4v p1, p2;
#pragma unroll
        for (int r = 0; r < 4; ++r) {
          p1[r] = f2b(acc[im][jn][r]);
          p2[r] = f2b(acc[im][jn + 2][r]);
        }
        const size_t off = (size_t)q4w * 128 + (size_t)l15r * 8 + e0;
        const size_t b1 = ((((size_t)bhi * 64 + kv32) * 4 + jo1) << 9) + off;
        const size_t b2 = ((((size_t)bhi * 64 + kv32) * 4 + jo1 + 2) << 9) + off;
        *(ushort4v*)(Vto + b1) = p1;
        *(ushort4v*)(Vto + b2) = p2;
      }
    }
  }
}

// ---- out-proj GEMM: NO LDS/barriers, 128x64 tile, 4 waves (32 rows each). ----
// 512 blocks = 2/CU. A=Yf (frag, written by attn), B=WoF (frag).
__global__ __launch_bounds__(256) void gemm_out(
    const u16* __restrict__ A, const u16* __restrict__ Bt,
    float* __restrict__ outf) {
  const int lane = threadIdx.x & 63, w = threadIdx.x >> 6;
  const int l15 = lane & 15, q4 = lane >> 4;
  const int g = blockIdx.x, xcd = g & 7, idx = g >> 3;  // idx 0..63
  const int bx = xcd * 2 + (idx & 1), by = idx >> 1;    // bx 0..15, by 0..31
  const int row0 = by * 128, col0 = bx * 64;
  const u16* Ab = A + (((size_t)((row0 >> 4) + w * 2) * 32) << 9) + lane * 8;
  const u16* Bb = Bt + (((size_t)(col0 >> 4) * 32) << 9) + lane * 8;

  f32x4 acc[2][4];
#pragma unroll
  for (int i = 0; i < 2; ++i)
#pragma unroll
    for (int j = 0; j < 4; ++j) acc[i][j] = (f32x4){0.f, 0.f, 0.f, 0.f};

  bf16x8 ac[2], an[2], bc[4], bn[4];
#pragma unroll
  for (int im = 0; im < 2; ++im) ac[im] = *(const bf16x8*)(Ab + ((size_t)(im * 32) << 9));
#pragma unroll
  for (int jn = 0; jn < 4; ++jn) bc[jn] = *(const bf16x8*)(Bb + ((size_t)(jn * 32) << 9));

  for (int t = 0; t < 32; t += 2) {
#pragma unroll
    for (int im = 0; im < 2; ++im) an[im] = *(const bf16x8*)(Ab + ((size_t)(im * 32 + t + 1) << 9));
#pragma unroll
    for (int jn = 0; jn < 4; ++jn) bn[jn] = *(const bf16x8*)(Bb + ((size_t)(jn * 32 + t + 1) << 9));
#pragma unroll
    for (int im = 0; im < 2; ++im)
#pragma unroll
      for (int jn = 0; jn < 4; ++jn)
        acc[im][jn] = __builtin_amdgcn_mfma_f32_16x16x32_bf16(ac[im], bc[jn], acc[im][jn], 0, 0, 0);
    if (t + 2 < 32) {
#pragma unroll
      for (int im = 0; im < 2; ++im) ac[im] = *(const bf16x8*)(Ab + ((size_t)(im * 32 + t + 2) << 9));
#pragma unroll
      for (int jn = 0; jn < 4; ++jn) bc[jn] = *(const bf16x8*)(Bb + ((size_t)(jn * 32 + t + 2) << 9));
    }
#pragma unroll
    for (int im = 0; im < 2; ++im)
#pragma unroll
      for (int jn = 0; jn < 4; ++jn)
        acc[im][jn] = __builtin_amdgcn_mfma_f32_16x16x32_bf16(an[im], bn[jn], acc[im][jn], 0, 0, 0);
  }

#pragma unroll
  for (int im = 0; im < 2; ++im) {
    const int rowb = row0 + w * 32 + im * 16 + q4 * 4;
#pragma unroll
    for (int jn = 0; jn < 4; ++jn) {
      const int n = col0 + jn * 16 + l15;
#pragma unroll
      for (int r = 0; r < 4; ++r)
        outf[(size_t)(rowb + r) * 1024 + n] = acc[im][jn][r];
    }
  }
}

// ---------------- windowed flash attention (R16 winner; Y now frag-ordered) ----------------
__global__ __launch_bounds__(256) void attn_k(
    const u16* __restrict__ Q, const u16* __restrict__ Kk,
    const u16* __restrict__ Vt, u16* __restrict__ Yf) {
  const int lane = threadIdx.x & 63, w = threadIdx.x >> 6;
  const int l15 = lane & 15, q4 = lane >> 4;
  const int hw = blockIdx.x;                    // 0..511
  const int work = (hw & 7) * 64 + (hw >> 3);   // XCD-chunked: each XCD owns 4 bh
  const int bh = work >> 4;
  const int qt = 15 - (work & 15);              // heavy first
  const int q0 = qt * 128 + w * 32;
  const int qt16 = q0 >> 4;

  bf16x8 bq[2][2];
#pragma unroll
  for (int qs = 0; qs < 2; ++qs)
#pragma unroll
    for (int kb = 0; kb < 2; ++kb)
      bq[qs][kb] = *(const bf16x8*)(Q + ((((size_t)bh * 128 + qt16 + qs) * 2 + kb) << 9) + lane * 8);

  f32x4 o[2][4];
#pragma unroll
  for (int qs = 0; qs < 2; ++qs)
#pragma unroll
    for (int jo = 0; jo < 4; ++jo) o[qs][jo] = (f32x4){0.f, 0.f, 0.f, 0.f};
  float lp[2] = {0.f, 0.f};

  int s0 = q0 - WIN_M1; if (s0 < 0) s0 = 0; s0 &= ~31;
  const int srcA = l15 + ((q4 & 1) << 5);
  const int srcB = srcA + 16;
  const bool lowq4 = (q4 < 2);

  bf16x8 kc[2][2], kn[2][2];
  bf16x8 vc[4], vn[4];
#pragma unroll
  for (int ks = 0; ks < 2; ++ks)
#pragma unroll
    for (int kb = 0; kb < 2; ++kb)
      kc[ks][kb] = *(const bf16x8*)(Kk + ((((size_t)bh * 128 + (s0 >> 4) + ks) * 2 + kb) << 9) + lane * 8);
#pragma unroll
  for (int jo = 0; jo < 4; ++jo)
    vc[jo] = *(const bf16x8*)(Vt + ((((size_t)bh * 64 + (s0 >> 5)) * 4 + jo) << 9) + lane * 8);

  int kv0 = s0;

#define TILE_BODY(KC, VC, KN, VN)                                                      \
  {                                                                                    \
    const int kvn = kv0 + 32;                                                          \
    if (kvn <= q0) {                                                                   \
      _Pragma("unroll") for (int ks = 0; ks < 2; ++ks)                                 \
          _Pragma("unroll") for (int kb = 0; kb < 2; ++kb)                             \
              KN[ks][kb] = *(const bf16x8*)(Kk +                                       \
                  ((((size_t)bh * 128 + (kvn >> 4) + ks) * 2 + kb) << 9) + lane * 8);  \
      _Pragma("unroll") for (int jo = 0; jo < 4; ++jo)                                 \
          VN[jo] = *(const bf16x8*)(Vt +                                               \
              ((((size_t)bh * 64 + (kvn >> 5)) * 4 + jo) << 9) + lane * 8);            \
    }                                                                                  \
    f32x4 ss[2][2];                                                                    \
    _Pragma("unroll") for (int ks = 0; ks < 2; ++ks)                                   \
        _Pragma("unroll") for (int qs = 0; qs < 2; ++qs)                               \
            ss[ks][qs] = (f32x4){0.f, 0.f, 0.f, 0.f};                                  \
    _Pragma("unroll") for (int kb = 0; kb < 2; ++kb)                                   \
        _Pragma("unroll") for (int ks = 0; ks < 2; ++ks)                               \
            _Pragma("unroll") for (int qs = 0; qs < 2; ++qs)                           \
                ss[ks][qs] = __builtin_amdgcn_mfma_f32_16x16x32_bf16(                  \
                    KC[ks][kb], bq[qs][kb], ss[ks][qs], 0, 0, 0);                      \
    if ((kv0 + 32 > q0) || (kv0 < q0 - 492)) {                                         \
      _Pragma("unroll") for (int qs = 0; qs < 2; ++qs) {                               \
        const int tq = q0 + qs * 16 + l15;                                             \
        _Pragma("unroll") for (int ks = 0; ks < 2; ++ks)                               \
            _Pragma("unroll") for (int r = 0; r < 4; ++r) {                            \
          const int kv = kv0 + ks * 16 + q4 * 4 + r;                                   \
          if (kv > tq || kv < tq - WIN_M1) ss[ks][qs][r] = MASKV;                      \
        }                                                                              \
      }                                                                                \
    }                                                                                  \
    _Pragma("unroll") for (int qs = 0; qs < 2; ++qs) {                                 \
      float p[2][4];                                                                   \
      _Pragma("unroll") for (int ks = 0; ks < 2; ++ks)                                 \
          _Pragma("unroll") for (int r = 0; r < 4; ++r)                                \
              p[ks][r] = fexp2(ss[ks][qs][r]);                                         \
      lp[qs] += ((p[0][0] + p[0][1]) + (p[0][2] + p[0][3])) +                          \
                ((p[1][0] + p[1][1]) + (p[1][2] + p[1][3]));                           \
      const u32 a0 = cvtpk(p[0][0], p[0][1]), a1 = cvtpk(p[0][2], p[0][3]);            \
      const u32 b0 = cvtpk(p[1][0], p[1][1]), b1 = cvtpk(p[1][2], p[1][3]);            \
      union { u32 d[4]; bf16x8 v; } pu;                                                \
      const u32 d0a = (u32)__shfl((int)a0, srcA), d0b = (u32)__shfl((int)b0, srcA);    \
      const u32 d1a = (u32)__shfl((int)a1, srcA), d1b = (u32)__shfl((int)b1, srcA);    \
      const u32 d2a = (u32)__shfl((int)a0, srcB), d2b = (u32)__shfl((int)b0, srcB);    \
      const u32 d3a = (u32)__shfl((int)a1, srcB), d3b = (u32)__shfl((int)b1, srcB);    \
      pu.d[0] = lowq4 ? d0a : d0b;                                                     \
      pu.d[1] = lowq4 ? d1a : d1b;                                                     \
      pu.d[2] = lowq4 ? d2a : d2b;                                                     \
      pu.d[3] = lowq4 ? d3a : d3b;                                                     \
      _Pragma("unroll") for (int jo = 0; jo < 4; ++jo)                                 \
          o[qs][jo] = __builtin_amdgcn_mfma_f32_16x16x32_bf16(pu.v, VC[jo],            \
                                                              o[qs][jo], 0, 0, 0);     \
    }                                                                                  \
  }

  while (true) {
    TILE_BODY(kc, vc, kn, vn);
    kv0 += 32; if (kv0 > q0) break;
    TILE_BODY(kn, vn, kc, vc);
    kv0 += 32; if (kv0 > q0) break;
  }
#undef TILE_BODY

  const int b = bh >> 4, h = bh & 15;
  const int r16base = (b * 2048 + q0) >> 4;
#pragma unroll
  for (int qs = 0; qs < 2; ++qs) {
    float l = lp[qs];
    l += __shfl_xor(l, 16);
    l += __shfl_xor(l, 32);
#pragma unroll
    for (int r = 0; r < 4; ++r) {
      const float lv = __shfl(l, q4 * 4 + r);
      const float inv = 1.0f / lv;
#pragma unroll
      for (int jo = 0; jo < 4; ++jo) {
        const int k32 = h * 2 + (jo >> 1);
        const int q4f = ((jo & 1) << 1) | (l15 >> 3);
        const size_t blk = ((size_t)(r16base + qs) * 32 + k32) << 9;
        const size_t off = (size_t)q4f * 128 + (size_t)(q4 * 4 + r) * 8 + (l15 & 7);
        Yf[blk + off] = f2b(o[qs][jo][r] * inv);
      }
    }
  }
}

extern "C" void kernel_launch(void* const* d_in, const int* in_sizes, int n_in,
                              void* d_out, int out_size, void* d_ws, size_t ws_size,
                              hipStream_t stream) {
  const float* x = (const float*)d_in[0];
  const float* Wq = (const float*)d_in[1];
  const float* Wk = (const float*)d_in[2];
  const float* Wv = (const float*)d_in[3];
  const float* Wo = (const float*)d_in[4];
  const float* rc = (const float*)d_in[5];
  const float* rs = (const float*)d_in[6];
  float* out = (float*)d_out;
  char* ws = (char*)d_ws;
  const size_t MB = 1024 * 1024;
  u16* xf = (u16*)(ws);               // frag-ordered x, 8MB
  u16* WcatF = (u16*)(ws + 8 * MB);   // frag-ordered Wq|Wk|Wv (3 regions), 6MB
  u16* WoF = (u16*)(ws + 14 * MB);    // frag-ordered Wo, 2MB
  u16* Qf = (u16*)(ws + 16 * MB);     // 8MB
  u16* Kf = (u16*)(ws + 24 * MB);     // 8MB
  u16* Vf = (u16*)(ws + 32 * MB);     // 8MB
  u16* Yf = (u16*)(ws + 40 * MB);     // frag-ordered Y, 8MB

  prep_k<<<8192, 256, 0, stream>>>(x, xf, Wq, Wk, Wv, Wo, WcatF, WoF);
  gemm_qkv<<<768, 256, 0, stream>>>(xf, WcatF, Qf, Kf, Vf, rc, rs);
  attn_k<<<512, 256, 0, stream>>>(Qf, Kf, Vf, Yf);
  gemm_out<<<512, 256, 0, stream>>>(Yf, WoF, out);
}

// Round 20
// 96.689 us; speedup vs baseline: 1.0876x; 1.0876x over previous
//
#include <hip/hip_runtime.h>
#include <math.h>

typedef unsigned short u16;
typedef unsigned int u32;
typedef __bf16 bf16x8 __attribute__((ext_vector_type(8)));
typedef float f32x4 __attribute__((ext_vector_type(4)));
typedef unsigned short ushort4v __attribute__((ext_vector_type(4)));

#define T_SEQ 2048
#define WIN_M1 523                 // WINDOW-1
#define QSCALE 0.180336879f        // 0.125 * log2(e): scores end up in log2 domain
#define MASKV -1e30f

__device__ __forceinline__ u16 f2b(float f) {
  union { float f; unsigned int u; } v; v.f = f;
  unsigned int u = v.u;
  u += 0x7FFFu + ((u >> 16) & 1u);
  return (u16)(u >> 16);
}

__device__ __forceinline__ u32 cvtpk(float lo, float hi) {
  union { __bf16 h[2]; u32 d; } cv;
  cv.h[0] = (__bf16)lo;
  cv.h[1] = (__bf16)hi;
  return cv.d;
}

__device__ __forceinline__ float fexp2(float x) {
  return __builtin_amdgcn_exp2f(x);
}

__device__ __forceinline__ void load_lds16(const u16* g, u16* l) {
  __builtin_amdgcn_global_load_lds(
      (const __attribute__((address_space(1))) void*)g,
      (__attribute__((address_space(3))) void*)l, 16, 0, 0);
}

// ===================== FRAGMENT-ORDERED TENSOR LAYOUTS (R16 win) ===========
//   Qf/Kf: [bh][t16=t/16][kb(2)][q4(4)][l15(16)][e(8)]
//   Vf:    [bh][kv32=kv/32][jo(4)][q4(4)][l15(16)][e(8)]
// Every attn load = base + lane*16B -> one contiguous 1KB segment/instr.
// ===========================================================================

// ---- fused prep: convert x (blocks 0..4095) + transpose 4 weights (blocks 4096..8191) ----
__global__ void prep_k(const float* __restrict__ x, u16* __restrict__ xb,
                       const float* __restrict__ W0, const float* __restrict__ W1,
                       const float* __restrict__ W2, const float* __restrict__ W3,
                       u16* __restrict__ WcatT, u16* __restrict__ WoT) {
  const int bid = blockIdx.x;
  if (bid < 4096) {
    int i = bid * 256 + threadIdx.x;
    float4 v = ((const float4*)x)[i];
    u16* d = xb + i * 4;
    d[0] = f2b(v.x); d[1] = f2b(v.y); d[2] = f2b(v.z); d[3] = f2b(v.w);
    return;
  }
  __shared__ float tile[32][33];
  const int t = bid - 4096;
  const int z = t >> 10, i = t & 1023;
  const float* W = (z == 0) ? W0 : (z == 1) ? W1 : (z == 2) ? W2 : W3;
  u16* Wt = (z < 3) ? (WcatT + (size_t)z * 1024 * 1024) : WoT;
  int tx = threadIdx.x & 31, ty = threadIdx.x >> 5;  // 32 x 8
  int n0 = (i & 31) * 32, k0 = (i >> 5) * 32;
#pragma unroll
  for (int j = 0; j < 4; ++j)
    tile[ty + j * 8][tx] = W[(size_t)(k0 + ty + j * 8) * 1024 + n0 + tx];
  __syncthreads();
#pragma unroll
  for (int j = 0; j < 4; ++j)
    Wt[(size_t)(n0 + ty + j * 8) * 1024 + k0 + tx] = f2b(tile[tx][ty + j * 8]);
}

// ---- 128x128 bf16 MFMA GEMM: 3-buf LDS (48KB), depth-2 vmcnt (R16 winner) ----
// R20: + XCD-chunked block mapping (T1). MODE 0 (768 blocks): each XCD owns
// 3 column-panels x 32 row-blocks -> B working set 768KB stays in its L2,
// reused 32x. MODE 1 (256 blocks): 1 column-panel per XCD (256KB).
// MODE 0: A=xb[4096][1024], Bt=WcatT[3072][1024] -> Qf/Kf (rope) + Vf
// MODE 1: A=Y [4096][1024], Bt=WoT [1024][1024] -> out fp32 row-major
template <int MODE>
__global__ __launch_bounds__(256, 4) void gemm_k(
    const u16* __restrict__ A, const u16* __restrict__ Bt,
    float* __restrict__ outf,
    u16* __restrict__ Qo, u16* __restrict__ Ko, u16* __restrict__ Vto,
    const float* __restrict__ rc, const float* __restrict__ rs) {
  __shared__ alignas(16) u16 As[3][128 * 32];
  __shared__ alignas(16) u16 Bs[3][128 * 32];
  const int tid = threadIdx.x, lane = tid & 63, w = tid >> 6;
  const int l15 = lane & 15, q4 = lane >> 4;
  // XCD-chunked bijective mapping (grid = 8 * 32 * CPX)
  constexpr int CPX = (MODE == 0) ? 3 : 1;  // column panels per XCD
  const int g = blockIdx.x, xcd = g & 7, idx = g >> 3;
  const int bx = xcd * CPX + idx % CPX, by = idx / CPX;
  const int row0 = by * 128, col0 = bx * 128;
  const int wm = w >> 1, wn = w & 1;
  constexpr int NT = 32;  // K=1024 / 32

  f32x4 acc[4][4];
#pragma unroll
  for (int i = 0; i < 4; ++i)
#pragma unroll
    for (int j = 0; j < 4; ++j) acc[i][j] = (f32x4){0.f, 0.f, 0.f, 0.f};

  const int off0 = (w * 2) * 1024 + lane * 16;
  const int r0 = off0 >> 6, c0 = (off0 & 63) >> 1;
  const int off1 = off0 + 1024;
  const int r1 = off1 >> 6, c1 = (off1 & 63) >> 1;
  const u16* gA0 = A + (size_t)(row0 + r0) * 1024 + c0;
  const u16* gA1 = A + (size_t)(row0 + r1) * 1024 + c1;
  const u16* gB0 = Bt + (size_t)(col0 + r0) * 1024 + c0;
  const u16* gB1 = Bt + (size_t)(col0 + r1) * 1024 + c1;
  const int soff = (w * 2) * 512;

  auto stage = [&](int buf, int t) {
    const int k0 = t * 32;
    load_lds16(gA0 + k0, &As[buf][soff]);
    load_lds16(gA1 + k0, &As[buf][soff + 512]);
    load_lds16(gB0 + k0, &Bs[buf][soff]);
    load_lds16(gB1 + k0, &Bs[buf][soff + 512]);
  };
  auto compute = [&](int buf) {
    bf16x8 af[4], bfr[4];
#pragma unroll
    for (int im = 0; im < 4; ++im)
      af[im] = *(const bf16x8*)&As[buf][(wm * 64 + im * 16 + l15) * 32 + q4 * 8];
#pragma unroll
    for (int jn = 0; jn < 4; ++jn)
      bfr[jn] = *(const bf16x8*)&Bs[buf][(wn * 64 + jn * 16 + l15) * 32 + q4 * 8];
#pragma unroll
    for (int im = 0; im < 4; ++im)
#pragma unroll
      for (int jn = 0; jn < 4; ++jn)
        acc[im][jn] = __builtin_amdgcn_mfma_f32_16x16x32_bf16(af[im], bfr[jn], acc[im][jn], 0, 0, 0);
  };

  stage(0, 0);
  stage(1, 1);
  int bs = 2, bc = 0;
  for (int t = 0; t + 2 < NT; ++t) {
    stage(bs, t + 2);
    asm volatile("s_waitcnt vmcnt(8)" ::: "memory");
    __builtin_amdgcn_s_barrier();
    compute(bc);
    __builtin_amdgcn_s_barrier();
    bs = (bs + 1 == 3) ? 0 : bs + 1;
    bc = (bc + 1 == 3) ? 0 : bc + 1;
  }
  asm volatile("s_waitcnt vmcnt(4)" ::: "memory");
  __builtin_amdgcn_s_barrier();
  compute(bc);
  __builtin_amdgcn_s_barrier();
  bc = (bc + 1 == 3) ? 0 : bc + 1;
  asm volatile("s_waitcnt vmcnt(0)" ::: "memory");
  __builtin_amdgcn_s_barrier();
  compute(bc);

  if constexpr (MODE == 0) {
#pragma unroll
    for (int im = 0; im < 4; ++im) {
      const int rowb = row0 + wm * 64 + im * 16 + q4 * 4;
      const int b = rowb >> 11, t0 = rowb & 2047;
#pragma unroll
      for (int jn = 0; jn < 2; ++jn) {
        const int n = col0 + wn * 64 + jn * 16 + l15;
        const int sel = n >> 10, nn = n & 1023;
        const int h = nn >> 6, hd = nn & 63;  // hd = jn*16+l15, in [0,32)
        const int bhi = b * 16 + h;
        if (sel < 2) {
          const float qs = (sel == 0) ? QSCALE : 1.0f;
          u16* base = (sel == 0 ? Qo : Ko);
          const int q4c = (hd >> 3) & 3, e = hd & 7;
#pragma unroll
          for (int r = 0; r < 4; ++r) {
            const int tt = t0 + r;
            const float c = rc[tt * 32 + hd], s = rs[tt * 32 + hd];
            const float x1 = acc[im][jn][r], x2 = acc[im][jn + 2][r];
            const size_t blk = ((size_t)bhi * 128 + (tt >> 4)) * 2;
            const size_t off = (size_t)q4c * 128 + (size_t)(tt & 15) * 8 + e;
            base[(blk << 9) + off] = f2b((x1 * c + x2 * s) * qs);
            base[((blk + 1) << 9) + off] = f2b((x1 * c - x2 * s) * qs);
          }
        } else {
          const int kv32 = t0 >> 5;
          const int q4w = (t0 >> 3) & 3;
          const int e0 = t0 & 7;           // in {0,4}
          const int jo1 = hd >> 4;         // = jn
          const int l15r = hd & 15;        // = l15
          ushort4v p1, p2;
#pragma unroll
          for (int r = 0; r < 4; ++r) {
            p1[r] = f2b(acc[im][jn][r]);
            p2[r] = f2b(acc[im][jn + 2][r]);
          }
          const size_t off = (size_t)q4w * 128 + (size_t)l15r * 8 + e0;
          const size_t b1 = ((((size_t)bhi * 64 + kv32) * 4 + jo1) << 9) + off;
          const size_t b2 = ((((size_t)bhi * 64 + kv32) * 4 + jo1 + 2) << 9) + off;
          *(ushort4v*)(Vto + b1) = p1;
          *(ushort4v*)(Vto + b2) = p2;
        }
      }
    }
  } else {
#pragma unroll
    for (int im = 0; im < 4; ++im) {
      const int rowb = row0 + wm * 64 + im * 16 + q4 * 4;
#pragma unroll
      for (int jn = 0; jn < 4; ++jn) {
        const int n = col0 + wn * 64 + jn * 16 + l15;
#pragma unroll
        for (int r = 0; r < 4; ++r)
          outf[(size_t)(rowb + r) * 1024 + n] = acc[im][jn][r];
      }
    }
  }
}

// ---------------- windowed flash attention (R16 winner, unchanged) ----------------
__global__ __launch_bounds__(256) void attn_k(
    const u16* __restrict__ Q, const u16* __restrict__ Kk,
    const u16* __restrict__ Vt, u16* __restrict__ Y) {
  const int lane = threadIdx.x & 63, w = threadIdx.x >> 6;
  const int l15 = lane & 15, q4 = lane >> 4;
  const int hw = blockIdx.x;                    // 0..511
  const int work = (hw & 7) * 64 + (hw >> 3);   // XCD-chunked: each XCD owns 4 bh
  const int bh = work >> 4;
  const int qt = 15 - (work & 15);              // heavy (large window) first
  const int q0 = qt * 128 + w * 32;
  const int qt16 = q0 >> 4;

  bf16x8 bq[2][2];
#pragma unroll
  for (int qs = 0; qs < 2; ++qs)
#pragma unroll
    for (int kb = 0; kb < 2; ++kb)
      bq[qs][kb] = *(const bf16x8*)(Q + ((((size_t)bh * 128 + qt16 + qs) * 2 + kb) << 9) + lane * 8);

  f32x4 o[2][4];
#pragma unroll
  for (int qs = 0; qs < 2; ++qs)
#pragma unroll
    for (int jo = 0; jo < 4; ++jo) o[qs][jo] = (f32x4){0.f, 0.f, 0.f, 0.f};
  float lp[2] = {0.f, 0.f};

  int s0 = q0 - WIN_M1; if (s0 < 0) s0 = 0; s0 &= ~31;
  const int srcA = l15 + ((q4 & 1) << 5);
  const int srcB = srcA + 16;
  const bool lowq4 = (q4 < 2);

  bf16x8 kc[2][2], kn[2][2];
  bf16x8 vc[4], vn[4];
#pragma unroll
  for (int ks = 0; ks < 2; ++ks)
#pragma unroll
    for (int kb = 0; kb < 2; ++kb)
      kc[ks][kb] = *(const bf16x8*)(Kk + ((((size_t)bh * 128 + (s0 >> 4) + ks) * 2 + kb) << 9) + lane * 8);
#pragma unroll
  for (int jo = 0; jo < 4; ++jo)
    vc[jo] = *(const bf16x8*)(Vt + ((((size_t)bh * 64 + (s0 >> 5)) * 4 + jo) << 9) + lane * 8);

  int kv0 = s0;

#define TILE_BODY(KC, VC, KN, VN)                                                      \
  {                                                                                    \
    const int kvn = kv0 + 32;                                                          \
    if (kvn <= q0) {                                                                   \
      _Pragma("unroll") for (int ks = 0; ks < 2; ++ks)                                 \
          _Pragma("unroll") for (int kb = 0; kb < 2; ++kb)                             \
              KN[ks][kb] = *(const bf16x8*)(Kk +                                       \
                  ((((size_t)bh * 128 + (kvn >> 4) + ks) * 2 + kb) << 9) + lane * 8);  \
      _Pragma("unroll") for (int jo = 0; jo < 4; ++jo)                                 \
          VN[jo] = *(const bf16x8*)(Vt +                                               \
              ((((size_t)bh * 64 + (kvn >> 5)) * 4 + jo) << 9) + lane * 8);            \
    }                                                                                  \
    f32x4 ss[2][2];                                                                    \
    _Pragma("unroll") for (int ks = 0; ks < 2; ++ks)                                   \
        _Pragma("unroll") for (int qs = 0; qs < 2; ++qs)                               \
            ss[ks][qs] = (f32x4){0.f, 0.f, 0.f, 0.f};                                  \
    _Pragma("unroll") for (int kb = 0; kb < 2; ++kb)                                   \
        _Pragma("unroll") for (int ks = 0; ks < 2; ++ks)                               \
            _Pragma("unroll") for (int qs = 0; qs < 2; ++qs)                           \
                ss[ks][qs] = __builtin_amdgcn_mfma_f32_16x16x32_bf16(                  \
                    KC[ks][kb], bq[qs][kb], ss[ks][qs], 0, 0, 0);                      \
    if ((kv0 + 32 > q0) || (kv0 < q0 - 492)) {                                         \
      _Pragma("unroll") for (int qs = 0; qs < 2; ++qs) {                               \
        const int tq = q0 + qs * 16 + l15;                                             \
        _Pragma("unroll") for (int ks = 0; ks < 2; ++ks)                               \
            _Pragma("unroll") for (int r = 0; r < 4; ++r) {                            \
          const int kv = kv0 + ks * 16 + q4 * 4 + r;                                   \
          if (kv > tq || kv < tq - WIN_M1) ss[ks][qs][r] = MASKV;                      \
        }                                                                              \
      }                                                                                \
    }                                                                                  \
    _Pragma("unroll") for (int qs = 0; qs < 2; ++qs) {                                 \
      float p[2][4];                                                                   \
      _Pragma("unroll") for (int ks = 0; ks < 2; ++ks)                                 \
          _Pragma("unroll") for (int r = 0; r < 4; ++r)                                \
              p[ks][r] = fexp2(ss[ks][qs][r]);                                         \
      lp[qs] += ((p[0][0] + p[0][1]) + (p[0][2] + p[0][3])) +                          \
                ((p[1][0] + p[1][1]) + (p[1][2] + p[1][3]));                           \
      const u32 a0 = cvtpk(p[0][0], p[0][1]), a1 = cvtpk(p[0][2], p[0][3]);            \
      const u32 b0 = cvtpk(p[1][0], p[1][1]), b1 = cvtpk(p[1][2], p[1][3]);            \
      union { u32 d[4]; bf16x8 v; } pu;                                                \
      const u32 d0a = (u32)__shfl((int)a0, srcA), d0b = (u32)__shfl((int)b0, srcA);    \
      const u32 d1a = (u32)__shfl((int)a1, srcA), d1b = (u32)__shfl((int)b1, srcA);    \
      const u32 d2a = (u32)__shfl((int)a0, srcB), d2b = (u32)__shfl((int)b0, srcB);    \
      const u32 d3a = (u32)__shfl((int)a1, srcB), d3b = (u32)__shfl((int)b1, srcB);    \
      pu.d[0] = lowq4 ? d0a : d0b;                                                     \
      pu.d[1] = lowq4 ? d1a : d1b;                                                     \
      pu.d[2] = lowq4 ? d2a : d2b;                                                     \
      pu.d[3] = lowq4 ? d3a : d3b;                                                     \
      _Pragma("unroll") for (int jo = 0; jo < 4; ++jo)                                 \
          o[qs][jo] = __builtin_amdgcn_mfma_f32_16x16x32_bf16(pu.v, VC[jo],            \
                                                              o[qs][jo], 0, 0, 0);     \
    }                                                                                  \
  }

  while (true) {
    TILE_BODY(kc, vc, kn, vn);
    kv0 += 32; if (kv0 > q0) break;
    TILE_BODY(kn, vn, kc, vc);
    kv0 += 32; if (kv0 > q0) break;
  }
#undef TILE_BODY

  const int b = bh >> 4, h = bh & 15;
  u16* Yb = Y + (size_t)(b * 2048 + q0) * 1024 + h * 64 + l15;
#pragma unroll
  for (int qs = 0; qs < 2; ++qs) {
    float l = lp[qs];
    l += __shfl_xor(l, 16);
    l += __shfl_xor(l, 32);
#pragma unroll
    for (int r = 0; r < 4; ++r) {
      const float lv = __shfl(l, q4 * 4 + r);
      const float inv = 1.0f / lv;
      u16* yr = Yb + (size_t)(qs * 16 + q4 * 4 + r) * 1024;
#pragma unroll
      for (int jo = 0; jo < 4; ++jo) yr[jo * 16] = f2b(o[qs][jo][r] * inv);
    }
  }
}

extern "C" void kernel_launch(void* const* d_in, const int* in_sizes, int n_in,
                              void* d_out, int out_size, void* d_ws, size_t ws_size,
                              hipStream_t stream) {
  const float* x = (const float*)d_in[0];
  const float* Wq = (const float*)d_in[1];
  const float* Wk = (const float*)d_in[2];
  const float* Wv = (const float*)d_in[3];
  const float* Wo = (const float*)d_in[4];
  const float* rc = (const float*)d_in[5];
  const float* rs = (const float*)d_in[6];
  float* out = (float*)d_out;
  char* ws = (char*)d_ws;
  const size_t MB = 1024 * 1024;
  u16* xb = (u16*)(ws);              // [4096][1024] 8MB
  u16* WcatT = (u16*)(ws + 8 * MB);  // [3072][1024] 6MB (Wq^T|Wk^T|Wv^T)
  u16* WoT = (u16*)(ws + 14 * MB);   // [1024][1024] 2MB
  u16* Qf = (u16*)(ws + 16 * MB);    // fragment-ordered Q, 8MB
  u16* Kf = (u16*)(ws + 24 * MB);    // fragment-ordered K, 8MB
  u16* Vf = (u16*)(ws + 32 * MB);    // fragment-ordered V, 8MB
  u16* Y = (u16*)(ws + 40 * MB);     // [4096][1024] 8MB

  prep_k<<<8192, 256, 0, stream>>>(x, xb, Wq, Wk, Wv, Wo, WcatT, WoT);
  gemm_k<0><<<768, 256, 0, stream>>>(xb, WcatT, nullptr, Qf, Kf, Vf, rc, rs);
  attn_k<<<512, 256, 0, stream>>>(Qf, Kf, Vf, Y);
  gemm_k<1><<<256, 256, 0, stream>>>(Y, WoT, out, nullptr, nullptr, nullptr, nullptr, nullptr);
}

// Round 21
// 94.926 us; speedup vs baseline: 1.1078x; 1.0186x over previous
//
#include <hip/hip_runtime.h>
#include <math.h>

typedef unsigned short u16;
typedef unsigned int u32;
typedef __bf16 bf16x8 __attribute__((ext_vector_type(8)));
typedef float f32x4 __attribute__((ext_vector_type(4)));
typedef unsigned short ushort4v __attribute__((ext_vector_type(4)));

#define T_SEQ 2048
#define WIN_M1 523                 // WINDOW-1
#define QSCALE 0.180336879f        // 0.125 * log2(e): scores end up in log2 domain
#define MASKV -1e30f

__device__ __forceinline__ u16 f2b(float f) {
  union { float f; unsigned int u; } v; v.f = f;
  unsigned int u = v.u;
  u += 0x7FFFu + ((u >> 16) & 1u);
  return (u16)(u >> 16);
}

// Packed f32->bf16 via COMPILER-generated conversion (hazard-safe vs v_exp
// TRANS producers -- R13/R14 lesson).
__device__ __forceinline__ u32 cvtpk(float lo, float hi) {
  union { __bf16 h[2]; u32 d; } cv;
  cv.h[0] = (__bf16)lo;
  cv.h[1] = (__bf16)hi;
  return cv.d;
}

__device__ __forceinline__ float fexp2(float x) {
  return __builtin_amdgcn_exp2f(x);
}

__device__ __forceinline__ void load_lds16(const u16* g, u16* l) {
  __builtin_amdgcn_global_load_lds(
      (const __attribute__((address_space(1))) void*)g,
      (__attribute__((address_space(3))) void*)l, 16, 0, 0);
}

// ===================== FRAGMENT-ORDERED TENSOR LAYOUTS (R16 win) ===========
//   Qf/Kf: [bh][t16=t/16][kb(2)][q4(4)][l15(16)][e(8)]
//   Vf:    [bh][kv32=kv/32][jo(4)][q4(4)][l15(16)][e(8)]
// Every attn load = base + lane*16B -> one contiguous 1KB segment/instr.
// ===========================================================================

// ---- fused prep: convert x (blocks 0..4095) + transpose 4 weights (blocks 4096..8191) ----
__global__ void prep_k(const float* __restrict__ x, u16* __restrict__ xb,
                       const float* __restrict__ W0, const float* __restrict__ W1,
                       const float* __restrict__ W2, const float* __restrict__ W3,
                       u16* __restrict__ WcatT, u16* __restrict__ WoT) {
  const int bid = blockIdx.x;
  if (bid < 4096) {
    int i = bid * 256 + threadIdx.x;
    float4 v = ((const float4*)x)[i];
    u16* d = xb + i * 4;
    d[0] = f2b(v.x); d[1] = f2b(v.y); d[2] = f2b(v.z); d[3] = f2b(v.w);
    return;
  }
  __shared__ float tile[32][33];
  const int t = bid - 4096;
  const int z = t >> 10, i = t & 1023;
  const float* W = (z == 0) ? W0 : (z == 1) ? W1 : (z == 2) ? W2 : W3;
  u16* Wt = (z < 3) ? (WcatT + (size_t)z * 1024 * 1024) : WoT;
  int tx = threadIdx.x & 31, ty = threadIdx.x >> 5;  // 32 x 8
  int n0 = (i & 31) * 32, k0 = (i >> 5) * 32;
#pragma unroll
  for (int j = 0; j < 4; ++j)
    tile[ty + j * 8][tx] = W[(size_t)(k0 + ty + j * 8) * 1024 + n0 + tx];
  __syncthreads();
#pragma unroll
  for (int j = 0; j < 4; ++j)
    Wt[(size_t)(n0 + ty + j * 8) * 1024 + k0 + tx] = f2b(tile[tx][ty + j * 8]);
}

// ---- 128x128 bf16 MFMA GEMM: 3-buf LDS (48KB), prefetch depth 2, counted vmcnt ----
// MODE 0: A=xb[4096][1024], Bt=WcatT[3072][1024] -> Qf/Kf (rope) + Vf, bf16
//         (fragment-ordered layouts above)
// MODE 1: A=Y [4096][1024], Bt=WoT [1024][1024] -> out fp32 row-major
template <int MODE>
__global__ __launch_bounds__(256, 4) void gemm_k(
    const u16* __restrict__ A, const u16* __restrict__ Bt,
    float* __restrict__ outf,
    u16* __restrict__ Qo, u16* __restrict__ Ko, u16* __restrict__ Vto,
    const float* __restrict__ rc, const float* __restrict__ rs) {
  __shared__ alignas(16) u16 As[3][128 * 32];
  __shared__ alignas(16) u16 Bs[3][128 * 32];
  const int tid = threadIdx.x, lane = tid & 63, w = tid >> 6;
  const int l15 = lane & 15, q4 = lane >> 4;
  const int row0 = blockIdx.y * 128, col0 = blockIdx.x * 128;
  const int wm = w >> 1, wn = w & 1;
  constexpr int NT = 32;  // K=1024 / 32

  f32x4 acc[4][4];
#pragma unroll
  for (int i = 0; i < 4; ++i)
#pragma unroll
    for (int j = 0; j < 4; ++j) acc[i][j] = (f32x4){0.f, 0.f, 0.f, 0.f};

  const int off0 = (w * 2) * 1024 + lane * 16;
  const int r0 = off0 >> 6, c0 = (off0 & 63) >> 1;
  const int off1 = off0 + 1024;
  const int r1 = off1 >> 6, c1 = (off1 & 63) >> 1;
  const u16* gA0 = A + (size_t)(row0 + r0) * 1024 + c0;
  const u16* gA1 = A + (size_t)(row0 + r1) * 1024 + c1;
  const u16* gB0 = Bt + (size_t)(col0 + r0) * 1024 + c0;
  const u16* gB1 = Bt + (size_t)(col0 + r1) * 1024 + c1;
  const int soff = (w * 2) * 512;

  auto stage = [&](int buf, int t) {
    const int k0 = t * 32;
    load_lds16(gA0 + k0, &As[buf][soff]);
    load_lds16(gA1 + k0, &As[buf][soff + 512]);
    load_lds16(gB0 + k0, &Bs[buf][soff]);
    load_lds16(gB1 + k0, &Bs[buf][soff + 512]);
  };
  auto compute = [&](int buf) {
    bf16x8 af[4], bfr[4];
#pragma unroll
    for (int im = 0; im < 4; ++im)
      af[im] = *(const bf16x8*)&As[buf][(wm * 64 + im * 16 + l15) * 32 + q4 * 8];
#pragma unroll
    for (int jn = 0; jn < 4; ++jn)
      bfr[jn] = *(const bf16x8*)&Bs[buf][(wn * 64 + jn * 16 + l15) * 32 + q4 * 8];
#pragma unroll
    for (int im = 0; im < 4; ++im)
#pragma unroll
      for (int jn = 0; jn < 4; ++jn)
        acc[im][jn] = __builtin_amdgcn_mfma_f32_16x16x32_bf16(af[im], bfr[jn], acc[im][jn], 0, 0, 0);
  };

  stage(0, 0);
  stage(1, 1);
  int bs = 2, bc = 0;
  for (int t = 0; t + 2 < NT; ++t) {
    stage(bs, t + 2);
    asm volatile("s_waitcnt vmcnt(8)" ::: "memory");
    __builtin_amdgcn_s_barrier();
    compute(bc);
    __builtin_amdgcn_s_barrier();
    bs = (bs + 1 == 3) ? 0 : bs + 1;
    bc = (bc + 1 == 3) ? 0 : bc + 1;
  }
  asm volatile("s_waitcnt vmcnt(4)" ::: "memory");
  __builtin_amdgcn_s_barrier();
  compute(bc);
  __builtin_amdgcn_s_barrier();
  bc = (bc + 1 == 3) ? 0 : bc + 1;
  asm volatile("s_waitcnt vmcnt(0)" ::: "memory");
  __builtin_amdgcn_s_barrier();
  compute(bc);

  if constexpr (MODE == 0) {
#pragma unroll
    for (int im = 0; im < 4; ++im) {
      const int rowb = row0 + wm * 64 + im * 16 + q4 * 4;
      const int b = rowb >> 11, t0 = rowb & 2047;
#pragma unroll
      for (int jn = 0; jn < 2; ++jn) {
        const int n = col0 + wn * 64 + jn * 16 + l15;
        const int sel = n >> 10, nn = n & 1023;
        const int h = nn >> 6, hd = nn & 63;  // hd = jn*16+l15, in [0,32)
        const int bhi = b * 16 + h;
        if (sel < 2) {
          const float qs = (sel == 0) ? QSCALE : 1.0f;
          u16* base = (sel == 0 ? Qo : Ko);
          const int q4c = (hd >> 3) & 3, e = hd & 7;
#pragma unroll
          for (int r = 0; r < 4; ++r) {
            const int tt = t0 + r;
            const float c = rc[tt * 32 + hd], s = rs[tt * 32 + hd];
            const float x1 = acc[im][jn][r], x2 = acc[im][jn + 2][r];
            const size_t blk = ((size_t)bhi * 128 + (tt >> 4)) * 2;
            const size_t off = (size_t)q4c * 128 + (size_t)(tt & 15) * 8 + e;
            base[(blk << 9) + off] = f2b((x1 * c + x2 * s) * qs);       // col hd   (kb=0)
            base[((blk + 1) << 9) + off] = f2b((x1 * c - x2 * s) * qs); // col hd+32(kb=1)
          }
        } else {
          // Vf: element (d=hd or hd+32, kv=t0+r). Per-lane: kv32,q4w const
          // over r; e = e0+r (4 consecutive) -> one ushort4 per jo.
          const int kv32 = t0 >> 5;
          const int q4w = (t0 >> 3) & 3;
          const int e0 = t0 & 7;           // in {0,4}
          const int jo1 = hd >> 4;         // = jn
          const int l15r = hd & 15;        // = l15
          ushort4v p1, p2;
#pragma unroll
          for (int r = 0; r < 4; ++r) {
            p1[r] = f2b(acc[im][jn][r]);
            p2[r] = f2b(acc[im][jn + 2][r]);
          }
          const size_t off = (size_t)q4w * 128 + (size_t)l15r * 8 + e0;
          const size_t b1 = ((((size_t)bhi * 64 + kv32) * 4 + jo1) << 9) + off;
          const size_t b2 = ((((size_t)bhi * 64 + kv32) * 4 + jo1 + 2) << 9) + off;
          *(ushort4v*)(Vto + b1) = p1;
          *(ushort4v*)(Vto + b2) = p2;
        }
      }
    }
  } else {
#pragma unroll
    for (int im = 0; im < 4; ++im) {
      const int rowb = row0 + wm * 64 + im * 16 + q4 * 4;
#pragma unroll
      for (int jn = 0; jn < 4; ++jn) {
        const int n = col0 + wn * 64 + jn * 16 + l15;
#pragma unroll
        for (int r = 0; r < 4; ++r)
          outf[(size_t)(rowb + r) * 1024 + n] = acc[im][jn][r];
      }
    }
  }
}

// ---------------- windowed flash attention, swapped-operand (S^T), FIXED-MAX ----------------
// Qf,Kf,Vf: fragment-ordered (see header). Y: [4096][1024] bf16.
// 4 waves/block, 32 q-rows/wave, KV tile 32, no LDS, K/V prefetch distance 1,
// fixed-max softmax, raw v_exp, shuffle P-relayout, K=32 PV. Every global
// load is base + lane*16B -- one contiguous 1KB segment per instruction.
__global__ __launch_bounds__(256) void attn_k(
    const u16* __restrict__ Q, const u16* __restrict__ Kk,
    const u16* __restrict__ Vt, u16* __restrict__ Y) {
  const int lane = threadIdx.x & 63, w = threadIdx.x >> 6;
  const int l15 = lane & 15, q4 = lane >> 4;
  const int hw = blockIdx.x;                    // 0..511
  const int work = (hw & 7) * 64 + (hw >> 3);   // XCD-chunked: each XCD owns 4 bh
  const int bh = work >> 4;
  const int qt = 15 - (work & 15);              // heavy (large window) first
  const int q0 = qt * 128 + w * 32;
  const int qt16 = q0 >> 4;

  bf16x8 bq[2][2];
#pragma unroll
  for (int qs = 0; qs < 2; ++qs)
#pragma unroll
    for (int kb = 0; kb < 2; ++kb)
      bq[qs][kb] = *(const bf16x8*)(Q + ((((size_t)bh * 128 + qt16 + qs) * 2 + kb) << 9) + lane * 8);

  f32x4 o[2][4];
#pragma unroll
  for (int qs = 0; qs < 2; ++qs)
#pragma unroll
    for (int jo = 0; jo < 4; ++jo) o[qs][jo] = (f32x4){0.f, 0.f, 0.f, 0.f};
  float lp[2] = {0.f, 0.f};  // per-lane partial denominators

  int s0 = q0 - WIN_M1; if (s0 < 0) s0 = 0; s0 &= ~31;
  const int srcA = l15 + ((q4 & 1) << 5);  // shuffle sources for P relayout
  const int srcB = srcA + 16;
  const bool lowq4 = (q4 < 2);

  bf16x8 kc[2][2], kn[2][2];
  bf16x8 vc[4], vn[4];
#pragma unroll
  for (int ks = 0; ks < 2; ++ks)
#pragma unroll
    for (int kb = 0; kb < 2; ++kb)
      kc[ks][kb] = *(const bf16x8*)(Kk + ((((size_t)bh * 128 + (s0 >> 4) + ks) * 2 + kb) << 9) + lane * 8);
#pragma unroll
  for (int jo = 0; jo < 4; ++jo)
    vc[jo] = *(const bf16x8*)(Vt + ((((size_t)bh * 64 + (s0 >> 5)) * 4 + jo) << 9) + lane * 8);

  int kv0 = s0;

#define TILE_BODY(KC, VC, KN, VN)                                                      \
  {                                                                                    \
    const int kvn = kv0 + 32;                                                          \
    if (kvn <= q0) {                                                                   \
      _Pragma("unroll") for (int ks = 0; ks < 2; ++ks)                                 \
          _Pragma("unroll") for (int kb = 0; kb < 2; ++kb)                             \
              KN[ks][kb] = *(const bf16x8*)(Kk +                                       \
                  ((((size_t)bh * 128 + (kvn >> 4) + ks) * 2 + kb) << 9) + lane * 8);  \
      _Pragma("unroll") for (int jo = 0; jo < 4; ++jo)                                 \
          VN[jo] = *(const bf16x8*)(Vt +                                               \
              ((((size_t)bh * 64 + (kvn >> 5)) * 4 + jo) << 9) + lane * 8);            \
    }                                                                                  \
    f32x4 ss[2][2];                                                                    \
    _Pragma("unroll") for (int ks = 0; ks < 2; ++ks)                                   \
        _Pragma("unroll") for (int qs = 0; qs < 2; ++qs)                               \
            ss[ks][qs] = (f32x4){0.f, 0.f, 0.f, 0.f};                                  \
    _Pragma("unroll") for (int kb = 0; kb < 2; ++kb)                                   \
        _Pragma("unroll") for (int ks = 0; ks < 2; ++ks)                               \
            _Pragma("unroll") for (int qs = 0; qs < 2; ++qs)                           \
                ss[ks][qs] = __builtin_amdgcn_mfma_f32_16x16x32_bf16(                  \
                    KC[ks][kb], bq[qs][kb], ss[ks][qs], 0, 0, 0);                      \
    if ((kv0 + 32 > q0) || (kv0 < q0 - 492)) {                                         \
      _Pragma("unroll") for (int qs = 0; qs < 2; ++qs) {                               \
        const int tq = q0 + qs * 16 + l15;                                             \
        _Pragma("unroll") for (int ks = 0; ks < 2; ++ks)                               \
            _Pragma("unroll") for (int r = 0; r < 4; ++r) {                            \
          const int kv = kv0 + ks * 16 + q4 * 4 + r;                                   \
          if (kv > tq || kv < tq - WIN_M1) ss[ks][qs][r] = MASKV;                      \
        }                                                                              \
      }                                                                                \
    }                                                                                  \
    _Pragma("unroll") for (int qs = 0; qs < 2; ++qs) {                                 \
      float p[2][4];                                                                   \
      _Pragma("unroll") for (int ks = 0; ks < 2; ++ks)                                 \
          _Pragma("unroll") for (int r = 0; r < 4; ++r)                                \
              p[ks][r] = fexp2(ss[ks][qs][r]);                                         \
      lp[qs] += ((p[0][0] + p[0][1]) + (p[0][2] + p[0][3])) +                          \
                ((p[1][0] + p[1][1]) + (p[1][2] + p[1][3]));                           \
      const u32 a0 = cvtpk(p[0][0], p[0][1]), a1 = cvtpk(p[0][2], p[0][3]);            \
      const u32 b0 = cvtpk(p[1][0], p[1][1]), b1 = cvtpk(p[1][2], p[1][3]);            \
      union { u32 d[4]; bf16x8 v; } pu;                                                \
      const u32 d0a = (u32)__shfl((int)a0, srcA), d0b = (u32)__shfl((int)b0, srcA);    \
      const u32 d1a = (u32)__shfl((int)a1, srcA), d1b = (u32)__shfl((int)b1, srcA);    \
      const u32 d2a = (u32)__shfl((int)a0, srcB), d2b = (u32)__shfl((int)b0, srcB);    \
      const u32 d3a = (u32)__shfl((int)a1, srcB), d3b = (u32)__shfl((int)b1, srcB);    \
      pu.d[0] = lowq4 ? d0a : d0b;                                                     \
      pu.d[1] = lowq4 ? d1a : d1b;                                                     \
      pu.d[2] = lowq4 ? d2a : d2b;                                                     \
      pu.d[3] = lowq4 ? d3a : d3b;                                                     \
      _Pragma("unroll") for (int jo = 0; jo < 4; ++jo)                                 \
          o[qs][jo] = __builtin_amdgcn_mfma_f32_16x16x32_bf16(pu.v, VC[jo],            \
                                                              o[qs][jo], 0, 0, 0);     \
    }                                                                                  \
  }

  while (true) {
    TILE_BODY(kc, vc, kn, vn);
    kv0 += 32; if (kv0 > q0) break;
    TILE_BODY(kn, vn, kc, vc);
    kv0 += 32; if (kv0 > q0) break;
  }
#undef TILE_BODY

  const int b = bh >> 4, h = bh & 15;
  u16* Yb = Y + (size_t)(b * 2048 + q0) * 1024 + h * 64 + l15;
#pragma unroll
  for (int qs = 0; qs < 2; ++qs) {
    float l = lp[qs];
    l += __shfl_xor(l, 16);
    l += __shfl_xor(l, 32);
#pragma unroll
    for (int r = 0; r < 4; ++r) {
      const float lv = __shfl(l, q4 * 4 + r);
      const float inv = 1.0f / lv;
      u16* yr = Yb + (size_t)(qs * 16 + q4 * 4 + r) * 1024;
#pragma unroll
      for (int jo = 0; jo < 4; ++jo) yr[jo * 16] = f2b(o[qs][jo][r] * inv);
    }
  }
}

extern "C" void kernel_launch(void* const* d_in, const int* in_sizes, int n_in,
                              void* d_out, int out_size, void* d_ws, size_t ws_size,
                              hipStream_t stream) {
  const float* x = (const float*)d_in[0];
  const float* Wq = (const float*)d_in[1];
  const float* Wk = (const float*)d_in[2];
  const float* Wv = (const float*)d_in[3];
  const float* Wo = (const float*)d_in[4];
  const float* rc = (const float*)d_in[5];
  const float* rs = (const float*)d_in[6];
  float* out = (float*)d_out;
  char* ws = (char*)d_ws;
  const size_t MB = 1024 * 1024;
  u16* xb = (u16*)(ws);              // [4096][1024] 8MB
  u16* WcatT = (u16*)(ws + 8 * MB);  // [3072][1024] 6MB (Wq^T|Wk^T|Wv^T)
  u16* WoT = (u16*)(ws + 14 * MB);   // [1024][1024] 2MB
  u16* Qf = (u16*)(ws + 16 * MB);    // fragment-ordered Q, 8MB
  u16* Kf = (u16*)(ws + 24 * MB);    // fragment-ordered K, 8MB
  u16* Vf = (u16*)(ws + 32 * MB);    // fragment-ordered V, 8MB
  u16* Y = (u16*)(ws + 40 * MB);     // [4096][1024] 8MB

  prep_k<<<8192, 256, 0, stream>>>(x, xb, Wq, Wk, Wv, Wo, WcatT, WoT);
  gemm_k<0><<<dim3(24, 32), 256, 0, stream>>>(xb, WcatT, nullptr, Qf, Kf, Vf, rc, rs);
  attn_k<<<512, 256, 0, stream>>>(Qf, Kf, Vf, Y);
  gemm_k<1><<<dim3(8, 32), 256, 0, stream>>>(Y, WoT, out, nullptr, nullptr, nullptr, nullptr, nullptr);
}